// Round 1
// baseline (522.460 us; speedup 1.0000x reference)
//
#include <hip/hip_runtime.h>
#include <hip/hip_bf16.h>

typedef short s16x8 __attribute__((ext_vector_type(8)));      // 8 bf16 (4 VGPRs)
typedef float f32x4 __attribute__((ext_vector_type(4)));
typedef unsigned short us8 __attribute__((ext_vector_type(8)));

#define HE   1024
#define SEQ  4096
#define NBAT 32
#define BM   64
#define BK   32
#define NKB  32          // HE / BK

__device__ __forceinline__ unsigned short f2bf(float f) {
    // round-to-nearest-even fp32 -> bf16
    unsigned u = __builtin_bit_cast(unsigned, f);
    u += 0x7FFFu + ((u >> 16) & 1u);
    return (unsigned short)(u >> 16);
}

__device__ __forceinline__ float tanh_fast(float x) {
    // tanh(x) = 1 - 2/(e^{2x}+1); v_exp-based, |rel err| ~1e-7, saturates correctly
    float e = __expf(2.0f * x);
    return 1.0f - 2.0f / (e + 1.0f);
}

// ---- h_proj partials: cpart[b][kc][h] = sum_{k in kc*128..} h[b,k] * W_attn[k,h]
__global__ void k_hproj(const float* __restrict__ hidden, const float* __restrict__ W,
                        float* __restrict__ cpart) {
    int b = blockIdx.x >> 3, kc = blockIdx.x & 7;
    int h = threadIdx.x;
    const float* hv = hidden + (NBAT + b) * HE;   // hidden[-1] = hidden[1]
    int k0 = kc * 128;
    float acc = 0.f;
    for (int j = 0; j < 128; ++j)
        acc = fmaf(hv[k0 + j], W[(k0 + j) * HE + h], acc);  // W_h = W_attn[:He]
    cpart[(b * 8 + kc) * HE + h] = acc;
}

// ---- c[b][h] = sum_kc cpart + b_attn[h]
__global__ void k_cfinal(const float* __restrict__ cpart, const float* __restrict__ b_attn,
                         float* __restrict__ c) {
    int b = blockIdx.x, h = threadIdx.x;
    float s = b_attn[h];
    #pragma unroll
    for (int kc = 0; kc < 8; ++kc) s += cpart[(b * 8 + kc) * HE + h];
    c[b * HE + h] = s;
}

// ---- pack W_e (= W_attn[He:]) into bf16 MFMA-B fragment order:
// Wp[((kb*64 + n16)*64 + lane)*8 + i] = bf16( W_e[kb*32 + (lane>>4)*8 + i][n16*16 + (lane&15)] )
__global__ void k_pack(const float* __restrict__ W, unsigned short* __restrict__ Wp) {
    int gid = blockIdx.x * blockDim.x + threadIdx.x;   // 32*64*64 = 131072 threads
    int l = gid & 63, n16 = (gid >> 6) & 63, kb = gid >> 12;
    int krow = HE + kb * 32 + ((l >> 4) * 8);
    int col = n16 * 16 + (l & 15);
    us8 v;
    #pragma unroll
    for (int i = 0; i < 8; ++i) v[i] = f2bf(W[(krow + i) * HE + col]);
    *(us8*)(Wp + (long)gid * 8) = v;
}

// ---- main fused kernel: 64 rows/block, full N=1024 in registers, epilogue fused
__global__ __launch_bounds__(512, 2) void k_main(
    const float* __restrict__ E, const us8* __restrict__ Wp,
    const float* __restrict__ C, const float* __restrict__ VW,
    float* __restrict__ scores)
{
    __shared__ unsigned short lds[2][BM * BK];   // 2 x 4 KB, XOR-swizzled bf16 E tile
    __shared__ float smred[BM][8];

    const int tid  = threadIdx.x;
    const int lane = tid & 63;
    const int wv   = tid >> 6;           // wave 0..7, owns cols wv*128..+127
    const int m0   = blockIdx.x * BM;    // global row base (m = b*4096 + s)
    const int bb   = m0 >> 12;           // batch index (uniform: 4096 % 64 == 0)

    // staging map: 512 threads x 4 floats = 64 rows x 32 k per BK step
    const int s_r = tid >> 3;            // row 0..63
    const int s_h = tid & 7;             // 4-float group 0..7
    const float* gE = E + (long)(m0 + s_r) * HE + s_h * 4;
    // 16B-chunk swizzle: chunk' = chunk ^ ((row>>1)&3)  -> 2-way banks on ds_read_b128 (free)
    const int s_off = s_r * 32 + (((s_h >> 1) ^ ((s_r >> 1) & 3)) * 8) + (s_h & 1) * 4;

    const int li = lane & 15;
    const int kg = lane >> 4;
    int a_off[4];
    #pragma unroll
    for (int rf = 0; rf < 4; ++rf) {
        int row = rf * 16 + li;          // (row>>1)&3 == (li>>1)&3 since rf*8 % 4 == 0
        a_off[rf] = row * 32 + ((kg ^ ((li >> 1) & 3)) * 8);
    }

    f32x4 acc[4][8];
    const f32x4 zero = {0.f, 0.f, 0.f, 0.f};
    #pragma unroll
    for (int rf = 0; rf < 4; ++rf)
        #pragma unroll
        for (int cf = 0; cf < 8; ++cf) acc[rf][cf] = zero;

    // prologue: stage kb=0 into buf 0
    {
        float4 v = *(const float4*)(gE);
        ushort4 o; o.x = f2bf(v.x); o.y = f2bf(v.y); o.z = f2bf(v.z); o.w = f2bf(v.w);
        *(ushort4*)(&lds[0][0] + s_off) = o;
    }
    __syncthreads();

    for (int kb = 0; kb < NKB; ++kb) {
        const int cur = kb & 1;
        float4 nv;
        if (kb + 1 < NKB) nv = *(const float4*)(gE + (kb + 1) * BK);  // issue early, hide under MFMA

        s16x8 bf[8];
        #pragma unroll
        for (int cf = 0; cf < 8; ++cf)
            bf[cf] = __builtin_bit_cast(s16x8, Wp[(long)(kb * 64 + wv * 8 + cf) * 64 + lane]);

        s16x8 af[4];
        #pragma unroll
        for (int rf = 0; rf < 4; ++rf)
            af[rf] = __builtin_bit_cast(s16x8, *(const us8*)(&lds[cur][0] + a_off[rf]));

        #pragma unroll
        for (int rf = 0; rf < 4; ++rf)
            #pragma unroll
            for (int cf = 0; cf < 8; ++cf)
                acc[rf][cf] = __builtin_amdgcn_mfma_f32_16x16x32_bf16(af[rf], bf[cf], acc[rf][cf], 0, 0, 0);

        if (kb + 1 < NKB) {
            ushort4 o; o.x = f2bf(nv.x); o.y = f2bf(nv.y); o.z = f2bf(nv.z); o.w = f2bf(nv.w);
            *(ushort4*)(&lds[cur ^ 1][0] + s_off) = o;
        }
        __syncthreads();
    }

    // fused epilogue: score[row] = sum_col v_w[col] * tanh(acc + c[b][col])
    float cv[8], vv[8];
    const int colbase = wv * 128 + li;
    #pragma unroll
    for (int cf = 0; cf < 8; ++cf) {
        cv[cf] = C[bb * HE + colbase + cf * 16];
        vv[cf] = VW[colbase + cf * 16];
    }
    #pragma unroll
    for (int rf = 0; rf < 4; ++rf) {
        #pragma unroll
        for (int rg = 0; rg < 4; ++rg) {
            float p = 0.f;
            #pragma unroll
            for (int cf = 0; cf < 8; ++cf)
                p += tanh_fast(acc[rf][cf][rg] + cv[cf]) * vv[cf];
            // reduce across the 16 lanes (same kg group) holding this row's columns
            p += __shfl_xor(p, 1);
            p += __shfl_xor(p, 2);
            p += __shfl_xor(p, 4);
            p += __shfl_xor(p, 8);
            if (li == 0) smred[rf * 16 + kg * 4 + rg][wv] = p;
        }
    }
    __syncthreads();
    if (tid < BM) {
        float s = 0.f;
        #pragma unroll
        for (int ww = 0; ww < 8; ++ww) s += smred[tid][ww];
        scores[m0 + tid] = s;
    }
}

// ---- softmax over S=4096 per batch row
__global__ void k_softmax(const float* __restrict__ scores, float* __restrict__ out) {
    __shared__ float red[16];
    __shared__ float red2[16];
    int b = blockIdx.x, tid = threadIdx.x;      // 1024 threads
    const float* s = scores + b * SEQ;
    float v[4];
    float mx = -1e30f;
    #pragma unroll
    for (int j = 0; j < 4; ++j) { v[j] = s[tid + j * 1024]; mx = fmaxf(mx, v[j]); }
    #pragma unroll
    for (int off = 32; off; off >>= 1) mx = fmaxf(mx, __shfl_xor(mx, off));
    if ((tid & 63) == 0) red[tid >> 6] = mx;
    __syncthreads();
    mx = red[0];
    #pragma unroll
    for (int i = 1; i < 16; ++i) mx = fmaxf(mx, red[i]);
    float sum = 0.f;
    #pragma unroll
    for (int j = 0; j < 4; ++j) { v[j] = expf(v[j] - mx); sum += v[j]; }
    #pragma unroll
    for (int off = 32; off; off >>= 1) sum += __shfl_xor(sum, off);
    if ((tid & 63) == 0) red2[tid >> 6] = sum;
    __syncthreads();
    sum = 0.f;
    #pragma unroll
    for (int i = 0; i < 16; ++i) sum += red2[i];
    float inv = 1.0f / sum;
    #pragma unroll
    for (int j = 0; j < 4; ++j) out[b * SEQ + tid + j * 1024] = v[j] * inv;
}

extern "C" void kernel_launch(void* const* d_in, const int* in_sizes, int n_in,
                              void* d_out, int out_size, void* d_ws, size_t ws_size,
                              hipStream_t stream)
{
    const float* hidden = (const float*)d_in[0];   // (2,32,1024) f32
    const float* enc    = (const float*)d_in[1];   // (32,4096,1024) f32
    const float* W      = (const float*)d_in[2];   // (2048,1024) f32
    const float* b_attn = (const float*)d_in[3];   // (1024,) f32
    const float* v_w    = (const float*)d_in[4];   // (1024,) f32
    float* out          = (float*)d_out;           // (32,4096) f32

    char* ws = (char*)d_ws;
    unsigned short* Wp = (unsigned short*)(ws);                        // 2 MB packed bf16 W_e
    float* cpart       = (float*)(ws + (2u << 20));                    // 1 MB
    float* Cc          = (float*)(ws + (3u << 20));                    // 128 KB
    float* scores      = (float*)(ws + (3u << 20) + (128u << 10));     // 512 KB

    k_pack   <<<512, 256,  0, stream>>>(W, Wp);
    k_hproj  <<<256, 1024, 0, stream>>>(hidden, W, cpart);
    k_cfinal <<<32,  1024, 0, stream>>>(cpart, b_attn, Cc);
    k_main   <<<2048, 512, 0, stream>>>(enc, (const us8*)Wp, Cc, v_w, scores);
    k_softmax<<<32,  1024, 0, stream>>>(scores, out);
}

// Round 2
// 420.303 us; speedup vs baseline: 1.2431x; 1.2431x over previous
//
#include <hip/hip_runtime.h>
#include <hip/hip_bf16.h>

typedef short s16x8 __attribute__((ext_vector_type(8)));      // 8 bf16 (4 VGPRs)
typedef float f32x4 __attribute__((ext_vector_type(4)));
typedef unsigned short us8 __attribute__((ext_vector_type(8)));

#define HE   1024
#define SEQ  4096
#define NBAT 32
#define BM   64
#define BK   32
#define NKB  32          // HE / BK

__device__ __forceinline__ unsigned short f2bf(float f) {
    unsigned u = __builtin_bit_cast(unsigned, f);
    u += 0x7FFFu + ((u >> 16) & 1u);
    return (unsigned short)(u >> 16);
}

__device__ __forceinline__ float tanh_fast(float x) {
    float e = __expf(2.0f * x);
    return 1.0f - 2.0f / (e + 1.0f);
}

// workgroup barrier WITHOUT vmcnt drain: only LDS ops (ds_write/ds_read) must
// be visible across waves; our global loads are register-destined and may
// stay in flight across the barrier (counted-vmcnt discipline, T4).
#define WG_SYNC() do {                                         \
    asm volatile("s_waitcnt lgkmcnt(0)" ::: "memory");         \
    __builtin_amdgcn_s_barrier();                              \
} while (0)

// ---- h_proj partials
__global__ void k_hproj(const float* __restrict__ hidden, const float* __restrict__ W,
                        float* __restrict__ cpart) {
    int b = blockIdx.x >> 3, kc = blockIdx.x & 7;
    int h = threadIdx.x;
    const float* hv = hidden + (NBAT + b) * HE;   // hidden[-1]
    int k0 = kc * 128;
    float acc = 0.f;
    for (int j = 0; j < 128; ++j)
        acc = fmaf(hv[k0 + j], W[(k0 + j) * HE + h], acc);
    cpart[(b * 8 + kc) * HE + h] = acc;
}

__global__ void k_cfinal(const float* __restrict__ cpart, const float* __restrict__ b_attn,
                         float* __restrict__ c) {
    int b = blockIdx.x, h = threadIdx.x;
    float s = b_attn[h];
    #pragma unroll
    for (int kc = 0; kc < 8; ++kc) s += cpart[(b * 8 + kc) * HE + h];
    c[b * HE + h] = s;
}

// ---- pack W_e into bf16 MFMA-B fragment order
__global__ void k_pack(const float* __restrict__ W, unsigned short* __restrict__ Wp) {
    int gid = blockIdx.x * blockDim.x + threadIdx.x;
    int l = gid & 63, n16 = (gid >> 6) & 63, kb = gid >> 12;
    int krow = HE + kb * 32 + ((l >> 4) * 8);
    int col = n16 * 16 + (l & 15);
    us8 v;
    #pragma unroll
    for (int i = 0; i < 8; ++i) v[i] = f2bf(W[(krow + i) * HE + col]);
    *(us8*)(Wp + (long)gid * 8) = v;
}

// ---- main fused kernel
__global__ __launch_bounds__(512, 2) void k_main(
    const float* __restrict__ E, const us8* __restrict__ Wp,
    const float* __restrict__ C, const float* __restrict__ VW,
    float* __restrict__ scores)
{
    __shared__ unsigned short lds[2][BM * BK];
    __shared__ float smred[BM][8];

    const int tid  = threadIdx.x;
    const int lane = tid & 63;
    const int wv   = tid >> 6;
    const int m0   = blockIdx.x * BM;
    const int bb   = m0 >> 12;

    const int s_r = tid >> 3;
    const int s_h = tid & 7;
    const float* gE = E + (long)(m0 + s_r) * HE + s_h * 4;
    const int s_off = s_r * 32 + (((s_h >> 1) ^ ((s_r >> 1) & 3)) * 8) + (s_h & 1) * 4;

    const int li = lane & 15;
    const int kg = lane >> 4;
    int a_off[4];
    #pragma unroll
    for (int rf = 0; rf < 4; ++rf) {
        int row = rf * 16 + li;
        a_off[rf] = row * 32 + ((kg ^ ((li >> 1) & 3)) * 8);
    }

    f32x4 acc[4][8];
    const f32x4 zero = {0.f, 0.f, 0.f, 0.f};
    #pragma unroll
    for (int rf = 0; rf < 4; ++rf)
        #pragma unroll
        for (int cf = 0; cf < 8; ++cf) acc[rf][cf] = zero;

#define LOADB(dst, kbi)                                                          \
    _Pragma("unroll")                                                            \
    for (int cf = 0; cf < 8; ++cf)                                               \
        dst[cf] = __builtin_bit_cast(s16x8,                                      \
            Wp[(long)(((kbi) * 64 + wv * 8 + cf) * 64 + lane)]);

#define STASH(buf, v) do {                                                       \
    ushort4 o_; o_.x = f2bf((v).x); o_.y = f2bf((v).y);                          \
    o_.z = f2bf((v).z); o_.w = f2bf((v).w);                                      \
    *(ushort4*)(&lds[buf][0] + s_off) = o_;                                      \
} while (0)

#define DO_MFMA(bfreg, buf) do {                                                 \
    s16x8 af_[4];                                                                \
    _Pragma("unroll")                                                            \
    for (int rf = 0; rf < 4; ++rf)                                               \
        af_[rf] = __builtin_bit_cast(s16x8, *(const us8*)(&lds[buf][0] + a_off[rf])); \
    _Pragma("unroll")                                                            \
    for (int rf = 0; rf < 4; ++rf)                                               \
        _Pragma("unroll")                                                        \
        for (int cf = 0; cf < 8; ++cf)                                           \
            acc[rf][cf] = __builtin_amdgcn_mfma_f32_16x16x32_bf16(               \
                af_[rf], bfreg[cf], acc[rf][cf], 0, 0, 0);                       \
} while (0)

    s16x8 bf0[8], bf1[8];
    float4 nv0, nv1;

    // prologue: B[0] into regs; E[0] staged direct; E[1],E[2] prefetched to regs
    LOADB(bf0, 0);
    {
        float4 v = *(const float4*)(gE);
        STASH(0, v);
    }
    nv0 = *(const float4*)(gE + 1 * BK);
    nv1 = *(const float4*)(gE + 2 * BK);
    WG_SYNC();   // lds[0] ready; nv0/nv1/bf0 stay in flight

    for (int kb = 0; kb < NKB; kb += 2) {
        // ---- even sub-iter: tile kb (lds[0], bf0) ----
        LOADB(bf1, kb + 1);                  // B prefetch for next tile (always valid)
        DO_MFMA(bf0, 0);
        STASH(1, nv0);                       // E[kb+1] -> lds[1]
        if (kb + 3 < NKB) nv0 = *(const float4*)(gE + (kb + 3) * BK);
        WG_SYNC();

        // ---- odd sub-iter: tile kb+1 (lds[1], bf1) ----
        if (kb + 2 < NKB) LOADB(bf0, kb + 2);
        DO_MFMA(bf1, 1);
        if (kb + 2 < NKB) STASH(0, nv1);     // E[kb+2] -> lds[0]
        if (kb + 4 < NKB) nv1 = *(const float4*)(gE + (kb + 4) * BK);
        WG_SYNC();
    }

#undef LOADB
#undef STASH
#undef DO_MFMA

    // fused epilogue: score[row] = sum_col v_w[col] * tanh(acc + c[b][col])
    float cv[8], vv[8];
    const int colbase = wv * 128 + li;
    #pragma unroll
    for (int cf = 0; cf < 8; ++cf) {
        cv[cf] = C[bb * HE + colbase + cf * 16];
        vv[cf] = VW[colbase + cf * 16];
    }
    #pragma unroll
    for (int rf = 0; rf < 4; ++rf) {
        #pragma unroll
        for (int rg = 0; rg < 4; ++rg) {
            float p = 0.f;
            #pragma unroll
            for (int cf = 0; cf < 8; ++cf)
                p += tanh_fast(acc[rf][cf][rg] + cv[cf]) * vv[cf];
            p += __shfl_xor(p, 1);
            p += __shfl_xor(p, 2);
            p += __shfl_xor(p, 4);
            p += __shfl_xor(p, 8);
            if (li == 0) smred[rf * 16 + kg * 4 + rg][wv] = p;
        }
    }
    __syncthreads();
    if (tid < BM) {
        float s = 0.f;
        #pragma unroll
        for (int ww = 0; ww < 8; ++ww) s += smred[tid][ww];
        scores[m0 + tid] = s;
    }
}

// ---- softmax over S=4096 per batch row
__global__ void k_softmax(const float* __restrict__ scores, float* __restrict__ out) {
    __shared__ float red[16];
    __shared__ float red2[16];
    int b = blockIdx.x, tid = threadIdx.x;
    const float* s = scores + b * SEQ;
    float v[4];
    float mx = -1e30f;
    #pragma unroll
    for (int j = 0; j < 4; ++j) { v[j] = s[tid + j * 1024]; mx = fmaxf(mx, v[j]); }
    #pragma unroll
    for (int off = 32; off; off >>= 1) mx = fmaxf(mx, __shfl_xor(mx, off));
    if ((tid & 63) == 0) red[tid >> 6] = mx;
    __syncthreads();
    mx = red[0];
    #pragma unroll
    for (int i = 1; i < 16; ++i) mx = fmaxf(mx, red[i]);
    float sum = 0.f;
    #pragma unroll
    for (int j = 0; j < 4; ++j) { v[j] = expf(v[j] - mx); sum += v[j]; }
    #pragma unroll
    for (int off = 32; off; off >>= 1) sum += __shfl_xor(sum, off);
    if ((tid & 63) == 0) red2[tid >> 6] = sum;
    __syncthreads();
    sum = 0.f;
    #pragma unroll
    for (int i = 0; i < 16; ++i) sum += red2[i];
    float inv = 1.0f / sum;
    #pragma unroll
    for (int j = 0; j < 4; ++j) out[b * SEQ + tid + j * 1024] = v[j] * inv;
}

extern "C" void kernel_launch(void* const* d_in, const int* in_sizes, int n_in,
                              void* d_out, int out_size, void* d_ws, size_t ws_size,
                              hipStream_t stream)
{
    const float* hidden = (const float*)d_in[0];
    const float* enc    = (const float*)d_in[1];
    const float* W      = (const float*)d_in[2];
    const float* b_attn = (const float*)d_in[3];
    const float* v_w    = (const float*)d_in[4];
    float* out          = (float*)d_out;

    char* ws = (char*)d_ws;
    unsigned short* Wp = (unsigned short*)(ws);
    float* cpart       = (float*)(ws + (2u << 20));
    float* Cc          = (float*)(ws + (3u << 20));
    float* scores      = (float*)(ws + (3u << 20) + (128u << 10));

    k_pack   <<<512, 256,  0, stream>>>(W, Wp);
    k_hproj  <<<256, 1024, 0, stream>>>(hidden, W, cpart);
    k_cfinal <<<32,  1024, 0, stream>>>(cpart, b_attn, Cc);
    k_main   <<<2048, 512, 0, stream>>>(enc, (const us8*)Wp, Cc, v_w, scores);
    k_softmax<<<32,  1024, 0, stream>>>(scores, out);
}

// Round 3
// 403.014 us; speedup vs baseline: 1.2964x; 1.0429x over previous
//
#include <hip/hip_runtime.h>
#include <hip/hip_bf16.h>

typedef short s16x8 __attribute__((ext_vector_type(8)));      // 8 bf16 (4 VGPRs)
typedef float f32x16 __attribute__((ext_vector_type(16)));
typedef unsigned short us8 __attribute__((ext_vector_type(8)));

#define HE   1024
#define SEQ  4096
#define NBAT 32
#define BM   64
#define BKG  128     // k per group (one barrier per group)
#define NG   8       // HE / BKG

__device__ __forceinline__ unsigned short f2bf(float f) {
    unsigned u = __builtin_bit_cast(unsigned, f);
    u += 0x7FFFu + ((u >> 16) & 1u);
    return (unsigned short)(u >> 16);
}

__device__ __forceinline__ float tanh_fast(float x) {
    float e = __expf(2.0f * x);
    return 1.0f - 2.0f / (e + 1.0f);
}

// barrier WITHOUT vmcnt drain: only LDS ops must be cross-wave visible;
// register-destined global loads stay in flight (counted-vmcnt discipline).
#define WG_SYNC() do {                                         \
    asm volatile("s_waitcnt lgkmcnt(0)" ::: "memory");         \
    __builtin_amdgcn_s_barrier();                              \
} while (0)

// ---- h_proj partials
__global__ void k_hproj(const float* __restrict__ hidden, const float* __restrict__ W,
                        float* __restrict__ cpart) {
    int b = blockIdx.x >> 3, kc = blockIdx.x & 7;
    int h = threadIdx.x;
    const float* hv = hidden + (NBAT + b) * HE;   // hidden[-1]
    int k0 = kc * 128;
    float acc = 0.f;
    for (int j = 0; j < 128; ++j)
        acc = fmaf(hv[k0 + j], W[(k0 + j) * HE + h], acc);
    cpart[(b * 8 + kc) * HE + h] = acc;
}

__global__ void k_cfinal(const float* __restrict__ cpart, const float* __restrict__ b_attn,
                         float* __restrict__ c) {
    int b = blockIdx.x, h = threadIdx.x;
    float s = b_attn[h];
    #pragma unroll
    for (int kc = 0; kc < 8; ++kc) s += cpart[(b * 8 + kc) * HE + h];
    c[b * HE + h] = s;
}

// ---- pack W_e (= W_attn[He:]) into 32x32x16 MFMA B-fragment order:
// Wp[((kb2*32 + cf)*64 + l)*8 + i] = bf16( W_e[kb2*16 + (l>>5)*8 + i][cf*32 + (l&31)] )
__global__ void k_pack(const float* __restrict__ W, unsigned short* __restrict__ Wp) {
    int gid = blockIdx.x * blockDim.x + threadIdx.x;   // 64*32*64 = 131072 threads
    int l = gid & 63, cf = (gid >> 6) & 31, kb2 = gid >> 11;
    int krow = HE + kb2 * 16 + ((l >> 5) * 8);
    int col  = cf * 32 + (l & 31);
    us8 v;
    #pragma unroll
    for (int i = 0; i < 8; ++i) v[i] = f2bf(W[(krow + i) * HE + col]);
    *(us8*)(Wp + (long)gid * 8) = v;
}

// ---- main fused kernel: 64 rows/block, full N=1024, 32x32x16 MFMA, K grouped by 128
__global__ __launch_bounds__(512, 2) void k_main(
    const float* __restrict__ E, const us8* __restrict__ Wp,
    const float* __restrict__ C, const float* __restrict__ VW,
    float* __restrict__ scores)
{
    __shared__ unsigned short Abuf[2][BM * BKG];   // 2 x 16 KB, swizzled bf16 E tile
    __shared__ float smred[BM][8];

    const int tid  = threadIdx.x;
    const int lane = tid & 63;
    const int wv   = tid >> 6;           // wave 0..7, cols wv*128..+127
    const int m0   = blockIdx.x * BM;
    const int bb   = m0 >> 12;

    // staging: 512 threads x 16 floats = 64 rows x 128 k per group
    const int s_row = tid >> 3;
    const int s_kc  = tid & 7;           // 16-float chunk within row
    const float* gE = E + (long)(m0 + s_row) * HE + s_kc * 16;
    const int s_sw  = s_row & 15;        // swizzle: 16B-unit ^= row&15
    const int s_w0  = s_row * 256 + ((((s_kc * 2) ^ s_sw)) << 4);
    const int s_w1  = s_row * 256 + ((((s_kc * 2 + 1) ^ s_sw)) << 4);

    // A-frag read map: row = rf*32 + (lane&31), k = h2*16 + (lane>>5)*8 + i
    const int l31 = lane & 31, lh = lane >> 5;
    const int a_sw = lane & 15;          // row&15 == lane&15 for both rf
    const int a_b0 = l31 * 256;
    const int a_b1 = (32 + l31) * 256;

    f32x16 acc[2][4];
    #pragma unroll
    for (int rf = 0; rf < 2; ++rf)
        #pragma unroll
        for (int cfi = 0; cfi < 4; ++cfi)
            #pragma unroll
            for (int e = 0; e < 16; ++e) acc[rf][cfi][e] = 0.f;

#define LOADB(dst, kb2i)                                                         \
    _Pragma("unroll")                                                            \
    for (int cfi = 0; cfi < 4; ++cfi)                                            \
        dst[cfi] = __builtin_bit_cast(s16x8,                                     \
            Wp[(long)(kb2i) * 2048 + (wv * 4 + cfi) * 64 + lane]);

#define AREAD(dst, base, h2i) do {                                               \
    dst = __builtin_bit_cast(s16x8, *(const us8*)((const char*)Ab +              \
            (base) + ((((h2i) * 2 + lh) ^ a_sw) << 4)));                         \
} while (0)

#define MFMA8(af, bf) do {                                                       \
    __builtin_amdgcn_s_setprio(1);                                               \
    _Pragma("unroll")                                                            \
    for (int rf = 0; rf < 2; ++rf)                                               \
        _Pragma("unroll")                                                        \
        for (int cfi = 0; cfi < 4; ++cfi)                                        \
            acc[rf][cfi] = __builtin_amdgcn_mfma_f32_32x32x16_bf16(              \
                af[rf], bf[cfi], acc[rf][cfi], 0, 0, 0);                         \
    __builtin_amdgcn_s_setprio(0);                                               \
} while (0)

#define STAGE_WRITE(buf) do {                                                    \
    us8 w0_, w1_;                                                                \
    w0_[0]=f2bf(ev0.x); w0_[1]=f2bf(ev0.y); w0_[2]=f2bf(ev0.z); w0_[3]=f2bf(ev0.w); \
    w0_[4]=f2bf(ev1.x); w0_[5]=f2bf(ev1.y); w0_[6]=f2bf(ev1.z); w0_[7]=f2bf(ev1.w); \
    w1_[0]=f2bf(ev2.x); w1_[1]=f2bf(ev2.y); w1_[2]=f2bf(ev2.z); w1_[3]=f2bf(ev2.w); \
    w1_[4]=f2bf(ev3.x); w1_[5]=f2bf(ev3.y); w1_[6]=f2bf(ev3.z); w1_[7]=f2bf(ev3.w); \
    *(us8*)((char*)&Abuf[buf][0] + s_w0) = w0_;                                  \
    *(us8*)((char*)&Abuf[buf][0] + s_w1) = w1_;                                  \
} while (0)

    s16x8 b0[4], b1[4];
    s16x8 a0[2], a1[2];
    float4 ev0, ev1, ev2, ev3;

    // prologue: stage group 0, preload B for kb2=0
    ev0 = *(const float4*)(gE + 0);
    ev1 = *(const float4*)(gE + 4);
    ev2 = *(const float4*)(gE + 8);
    ev3 = *(const float4*)(gE + 12);
    LOADB(b0, 0);
    STAGE_WRITE(0);
    WG_SYNC();

    for (int g = 0; g < NG; ++g) {
        const int p = g & 1;
        const unsigned short* Ab = &Abuf[p][0];

        // issue E loads for group g+1 (consumed at group end -> ~8 phases of slack)
        if (g + 1 < NG) {
            const float* gn = gE + (g + 1) * BKG;
            ev0 = *(const float4*)(gn + 0);
            ev1 = *(const float4*)(gn + 4);
            ev2 = *(const float4*)(gn + 8);
            ev3 = *(const float4*)(gn + 12);
        }

        AREAD(a0[0], a_b0, 0);
        AREAD(a0[1], a_b1, 0);

        #pragma unroll
        for (int h2 = 0; h2 < 8; h2 += 2) {
            const int kb2 = g * 8 + h2;
            // even phase: compute (a0,b0); prefetch b1/a1 for h2+1
            LOADB(b1, kb2 + 1);                       // kb2+1 <= 63 always here
            AREAD(a1[0], a_b0, h2 + 1);
            AREAD(a1[1], a_b1, h2 + 1);
            MFMA8(a0, b0);
            // odd phase: compute (a1,b1); prefetch b0/a0 for h2+2
            {
                int nk = kb2 + 2; if (nk > 63) nk = 63;   // clamp (last group tail)
                LOADB(b0, nk);
            }
            if (h2 + 2 < 8) {
                AREAD(a0[0], a_b0, h2 + 2);
                AREAD(a0[1], a_b1, h2 + 2);
            }
            MFMA8(a1, b1);
        }

        if (g + 1 < NG) STAGE_WRITE(1 - p);
        WG_SYNC();
    }

#undef LOADB
#undef AREAD
#undef MFMA8
#undef STAGE_WRITE

    // fused epilogue: score[row] = sum_col v_w[col] * tanh(acc + c[b][col])
    float cv[4], vv[4];
    #pragma unroll
    for (int cfi = 0; cfi < 4; ++cfi) {
        int col = wv * 128 + cfi * 32 + l31;
        cv[cfi] = C[bb * HE + col];
        vv[cfi] = VW[col];
    }
    #pragma unroll
    for (int rf = 0; rf < 2; ++rf) {
        #pragma unroll
        for (int reg = 0; reg < 16; ++reg) {
            float pS = 0.f;
            #pragma unroll
            for (int cfi = 0; cfi < 4; ++cfi)
                pS += tanh_fast(acc[rf][cfi][reg] + cv[cfi]) * vv[cfi];
            // reduce across the 32 lanes holding this row's columns
            pS += __shfl_xor(pS, 1);
            pS += __shfl_xor(pS, 2);
            pS += __shfl_xor(pS, 4);
            pS += __shfl_xor(pS, 8);
            pS += __shfl_xor(pS, 16);
            if (l31 == 0) {
                int row = rf * 32 + (reg & 3) + 8 * (reg >> 2) + 4 * lh;
                smred[row][wv] = pS;
            }
        }
    }
    __syncthreads();
    if (tid < BM) {
        float s = 0.f;
        #pragma unroll
        for (int ww = 0; ww < 8; ++ww) s += smred[tid][ww];
        scores[m0 + tid] = s;
    }
}

// ---- softmax over S=4096 per batch row
__global__ void k_softmax(const float* __restrict__ scores, float* __restrict__ out) {
    __shared__ float red[16];
    __shared__ float red2[16];
    int b = blockIdx.x, tid = threadIdx.x;
    const float* s = scores + b * SEQ;
    float v[4];
    float mx = -1e30f;
    #pragma unroll
    for (int j = 0; j < 4; ++j) { v[j] = s[tid + j * 1024]; mx = fmaxf(mx, v[j]); }
    #pragma unroll
    for (int off = 32; off; off >>= 1) mx = fmaxf(mx, __shfl_xor(mx, off));
    if ((tid & 63) == 0) red[tid >> 6] = mx;
    __syncthreads();
    mx = red[0];
    #pragma unroll
    for (int i = 1; i < 16; ++i) mx = fmaxf(mx, red[i]);
    float sum = 0.f;
    #pragma unroll
    for (int j = 0; j < 4; ++j) { v[j] = expf(v[j] - mx); sum += v[j]; }
    #pragma unroll
    for (int off = 32; off; off >>= 1) sum += __shfl_xor(sum, off);
    if ((tid & 63) == 0) red2[tid >> 6] = sum;
    __syncthreads();
    sum = 0.f;
    #pragma unroll
    for (int i = 0; i < 16; ++i) sum += red2[i];
    float inv = 1.0f / sum;
    #pragma unroll
    for (int j = 0; j < 4; ++j) out[b * SEQ + tid + j * 1024] = v[j] * inv;
}

extern "C" void kernel_launch(void* const* d_in, const int* in_sizes, int n_in,
                              void* d_out, int out_size, void* d_ws, size_t ws_size,
                              hipStream_t stream)
{
    const float* hidden = (const float*)d_in[0];
    const float* enc    = (const float*)d_in[1];
    const float* W      = (const float*)d_in[2];
    const float* b_attn = (const float*)d_in[3];
    const float* v_w    = (const float*)d_in[4];
    float* out          = (float*)d_out;

    char* ws = (char*)d_ws;
    unsigned short* Wp = (unsigned short*)(ws);                        // 2 MB packed bf16 W_e
    float* cpart       = (float*)(ws + (2u << 20));                    // 1 MB
    float* Cc          = (float*)(ws + (3u << 20));                    // 128 KB
    float* scores      = (float*)(ws + (3u << 20) + (128u << 10));     // 512 KB

    k_pack   <<<512, 256,  0, stream>>>(W, Wp);
    k_hproj  <<<256, 1024, 0, stream>>>(hidden, W, cpart);
    k_cfinal <<<32,  1024, 0, stream>>>(cpart, b_attn, Cc);
    k_main   <<<2048, 512, 0, stream>>>(enc, (const us8*)Wp, Cc, v_w, scores);
    k_softmax<<<32,  1024, 0, stream>>>(scores, out);
}